// Round 7
// baseline (539.632 us; speedup 1.0000x reference)
//
#include <hip/hip_runtime.h>
#include <hip/hip_bf16.h>

#define Tt   16384
#define Dd   1024
#define Ee   8
#define CAP  2048
#define DFFf 4096

typedef __attribute__((ext_vector_type(8))) short bf16x8;
typedef __attribute__((ext_vector_type(4))) float f32x4;

__device__ __forceinline__ unsigned short f2bf(float f) {
  union { float f; unsigned u; } v; v.f = f;
  unsigned r = (v.u + 0x7FFFu + ((v.u >> 16) & 1u)) >> 16;
  return (unsigned short)r;
}

__device__ __forceinline__ float gelu_tanh(float x) {
  float z = 0.7978845608028654f * (x + 0.044715f * x * x * x);
  float az = fabsf(z);
  float t = __expf(-2.0f * az);
  float th = (1.0f - t) / (1.0f + t);
  th = (z < 0.0f) ? -th : th;
  return 0.5f * x * (1.0f + th);
}

__device__ __forceinline__ void gld16(const void* g, void* l) {
  __builtin_amdgcn_global_load_lds(
      (const __attribute__((address_space(1))) void*)g,
      (__attribute__((address_space(3))) void*)l,
      16, 0, 0);
}

template <int IMM>
__device__ __forceinline__ bf16x8 dsr(unsigned a) {
  bf16x8 r;
  asm volatile("ds_read_b128 %0, %1 offset:%c2" : "=v"(r) : "v"(a), "i"(IMM));
  return r;
}
#define LGKM(N) asm volatile("s_waitcnt lgkmcnt(" #N ")" ::: "memory")
#define VMCNT(N) asm volatile("s_waitcnt vmcnt(" #N ")" ::: "memory")

// ---------------- gating: logits fp32, softmax, argmax ----------------
__global__ __launch_bounds__(256) void gating_kernel(
    const float* __restrict__ x, const float* __restrict__ wg,
    int* __restrict__ idx, float* __restrict__ gate, float* __restrict__ meP) {
  int tid = threadIdx.x, lane = tid & 63, w = tid >> 6;
  int t = blockIdx.x * 4 + w;
  const float* xr = x + (size_t)t * Dd;
  float p[8];
#pragma unroll
  for (int e2 = 0; e2 < 8; ++e2) p[e2] = 0.f;
#pragma unroll
  for (int i = 0; i < 16; ++i) {
    int j = lane + (i << 6);
    float xv = xr[j];
    const float4* wr = (const float4*)(wg + j * 8);
    float4 a = wr[0], b = wr[1];
    p[0] += xv * a.x; p[1] += xv * a.y; p[2] += xv * a.z; p[3] += xv * a.w;
    p[4] += xv * b.x; p[5] += xv * b.y; p[6] += xv * b.z; p[7] += xv * b.w;
  }
#pragma unroll
  for (int off = 32; off > 0; off >>= 1)
#pragma unroll
    for (int e2 = 0; e2 < 8; ++e2) p[e2] += __shfl_xor(p[e2], off);
  __shared__ float smG[4][8];
  if (lane == 0) {
    float mx = p[0]; int am = 0;
#pragma unroll
    for (int e2 = 1; e2 < 8; ++e2) if (p[e2] > mx) { mx = p[e2]; am = e2; }
    float s = 0.f, g2[8];
#pragma unroll
    for (int e2 = 0; e2 < 8; ++e2) { g2[e2] = __expf(p[e2] - mx); s += g2[e2]; }
    float inv = 1.f / s;
    idx[t] = am;
    gate[t] = g2[am] * inv;
#pragma unroll
    for (int e2 = 0; e2 < 8; ++e2) smG[w][e2] = g2[e2] * inv;
  }
  __syncthreads();
  if (tid < 8)
    meP[blockIdx.x * 8 + tid] = smG[0][tid] + smG[1][tid] + smG[2][tid] + smG[3][tid];
}

// ------------- scan: per-expert cumulative position + l_aux -------------
__global__ __launch_bounds__(512) void scan_kernel(
    const int* __restrict__ idx, int* __restrict__ pos, int* __restrict__ smap,
    const float* __restrict__ meP, int nblkG, float* __restrict__ laux_out) {
  int tid = threadIdx.x, lane = tid & 63, e = tid >> 6;
  int running = 0;
  for (int c = 0; c < Tt; c += 256) {
    int m0 = idx[c + lane];
    int m1 = idx[c + 64 + lane];
    int m2 = idx[c + 128 + lane];
    int m3 = idx[c + 192 + lane];
#define RND(mv, base) { \
    unsigned long long mm = __ballot(mv == e); \
    int p = running + __popcll(mm & ((1ull << lane) - 1ull)); \
    if (mv == e) { pos[(base) + lane] = p; if (p < CAP) smap[e * CAP + p] = (base) + lane; } \
    running += (int)__popcll(mm); }
    RND(m0, c) RND(m1, c + 64) RND(m2, c + 128) RND(m3, c + 192)
#undef RND
  }
  __shared__ int scnt[8];
  __shared__ float smesum[8];
  __shared__ float red[512];
  if (lane == 0) scnt[e] = running;
  float part = 0.f;
  int ee = tid & 7, b0 = tid >> 3;
  for (int b = b0; b < nblkG; b += 64) part += meP[b * 8 + ee];
  red[tid] = part;
  __syncthreads();
  if (tid < 8) {
    float s = 0.f;
    for (int i = 0; i < 64; ++i) s += red[i * 8 + tid];
    smesum[tid] = s;
  }
  __syncthreads();
  if (tid == 0) {
    float l = 0.f;
    for (int q = 0; q < 8; ++q) l += smesum[q] * (float)scnt[q];
    laux_out[0] = l * 8.0f / ((float)Tt * (float)Tt);
  }
}

// ------------- zero dropped-token output rows -------------
__global__ __launch_bounds__(256) void zero_dropped(
    const int* __restrict__ pos, float* __restrict__ out) {
  int t = blockIdx.x;
  if (pos[t] < CAP) return;
  ((float4*)(out + (size_t)t * Dd))[threadIdx.x] = make_float4(0.f, 0.f, 0.f, 0.f);
}

// ------------- transpose + cast fp32 -> bf16 (B^T weight layout) -------------
__global__ __launch_bounds__(256) void transpose_cast(
    const float* __restrict__ src, unsigned short* __restrict__ dst, int R, int Cn) {
  __shared__ float tile[64][65];
  int e = blockIdx.z;
  const float* s = src + (size_t)e * R * Cn;
  unsigned short* d = dst + (size_t)e * R * Cn;
  int c = threadIdx.x & 63;
  int r0 = threadIdx.x >> 6;
  int rb = blockIdx.y * 64, cb = blockIdx.x * 64;
#pragma unroll
  for (int i = 0; i < 16; ++i) {
    int r = r0 + i * 4;
    tile[r][c] = s[(size_t)(rb + r) * Cn + cb + c];
  }
  __syncthreads();
#pragma unroll
  for (int i = 0; i < 16; ++i) {
    int r = r0 + i * 4;
    d[(size_t)(cb + r) * R + rb + c] = f2bf(tile[c][r]);
  }
}

// ------------- gather + cast dispatched tokens -------------
__global__ __launch_bounds__(256) void build_xg(
    const float* __restrict__ x, const int* __restrict__ smap,
    unsigned short* __restrict__ Xg) {
  int row = blockIdx.x;
  int t = smap[row];
  int j = threadIdx.x;
  float4 v = make_float4(0.f, 0.f, 0.f, 0.f);
  if (t >= 0) v = ((const float4*)(x + (size_t)t * Dd))[j];
  ushort4 o;
  o.x = f2bf(v.x); o.y = f2bf(v.y); o.z = f2bf(v.z); o.w = f2bf(v.w);
  ((ushort4*)(Xg + (size_t)row * Dd))[j] = o;
}

// ------------- 128x256-tile bf16 MFMA GEMM (B^T), BK=32, 2 blocks/CU ---------
// 256 threads = 4 waves (2M x 2N), wave-tile 64x128. LDS 56 KB (2 slots of
// 32 KB stride: A 8 KB + B 16 KB used). Cross-block TLP hides drains (m97).
// 64-B-row layout, granule swizzle g' = g ^ (row&3): reads hit all 8 widebanks
// evenly (BW floor, 0 conflicts); staging dest linear (gload_lds-safe).
template <int DO_GELU, int FUSE_COMBINE>
__global__ __launch_bounds__(256, 2) void gemm128_kernel(
    const unsigned short* __restrict__ A,   // [E][M][K] bf16
    const unsigned short* __restrict__ BT,  // [E][N][K] bf16
    unsigned short* __restrict__ Hout,      // [E][M][N] bf16 (GEMM1)
    const int* __restrict__ smap,           // [E][CAP] token map (GEMM2)
    const float* __restrict__ gate,         // [T]
    float* __restrict__ out,                // [T][D]
    int M, int N, int K) {
  __shared__ char lds[57344];  // slot s at s*32768: [A 8K][B 16K]
  int tid = threadIdx.x, lane = tid & 63, w = tid >> 6;
  int wm = w >> 1, wn = w & 1;

  // bijective XCD-aware swizzle; bm fastest within chunk (B-strip L2 reuse)
  int gx = gridDim.x, gy = gridDim.y;
  long gid = blockIdx.x + (long)gx * (blockIdx.y + (long)gy * blockIdx.z);
  int nT = gx * gy * (int)gridDim.z;
  int cpx = nT >> 3;
  int swz = (int)((gid & 7) * (long)cpx + (gid >> 3));
  int bm = swz % gx;
  int bn = (swz / gx) % gy;
  int e  = swz / (gx * gy);

  const unsigned short* Ab = A + ((size_t)e * M + (size_t)bm * 128) * K;
  const unsigned short* Bb = BT + ((size_t)e * N + (size_t)bn * 256) * K;

  // staging source offsets: region-local phys p -> row=p>>6, g'=((p>>4)&3)^(row&3)
  unsigned svA[2], svB[4];
#pragma unroll
  for (int q = 0; q < 2; ++q) {
    int p = q * 4096 + tid * 16;
    int row = p >> 6;
    svA[q] = (unsigned)(row * (K * 2) + ((((p >> 4) & 3) ^ (row & 3)) << 4));
  }
#pragma unroll
  for (int q = 0; q < 4; ++q) {
    int p = q * 4096 + tid * 16;
    int row = p >> 6;
    svB[q] = (unsigned)(row * (K * 2) + ((((p >> 4) & 3) ^ (row & 3)) << 4));
  }

#define STAGE(S, T) { \
    const char* As_ = (const char*)Ab + (unsigned)(T) * 64u; \
    const char* Bs_ = (const char*)Bb + (unsigned)(T) * 64u; \
    char* d_ = lds + (S) * 32768 + tid * 16; \
    gld16(As_ + svA[0], d_); \
    gld16(As_ + svA[1], d_ + 4096); \
    gld16(Bs_ + svB[0], d_ + 8192); \
    gld16(Bs_ + svB[1], d_ + 12288); \
    gld16(Bs_ + svB[2], d_ + 16384); \
    gld16(Bs_ + svB[3], d_ + 20480); }

  // fragment LDS addresses (slot 0), swizzle folded; +16-row frag step = +1024B
  unsigned lb = (unsigned)(size_t)(__attribute__((address_space(3))) char*)lds;
  int arow = wm * 64 + (lane & 15);
  int brow = wn * 128 + (lane & 15);
  unsigned g = (unsigned)(lane >> 4);
  unsigned aAd = lb + (unsigned)(arow * 64) + ((g ^ (unsigned)(arow & 3)) << 4);
  unsigned bAd = lb + 8192u + (unsigned)(brow * 64) + ((g ^ (unsigned)(brow & 3)) << 4);

  f32x4 acc[4][8];
#pragma unroll
  for (int mi = 0; mi < 4; ++mi)
#pragma unroll
    for (int n = 0; n < 8; ++n) acc[mi][n] = (f32x4){0.f, 0.f, 0.f, 0.f};

  bf16x8 af[4], bf0[4], bf1[4];
#define READS_ { \
    af[0] = dsr<0>(aAd); af[1] = dsr<1024>(aAd); af[2] = dsr<2048>(aAd); af[3] = dsr<3072>(aAd); \
    bf0[0] = dsr<0>(bAd); bf0[1] = dsr<1024>(bAd); bf0[2] = dsr<2048>(bAd); bf0[3] = dsr<3072>(bAd); \
    bf1[0] = dsr<4096>(bAd); bf1[1] = dsr<5120>(bAd); bf1[2] = dsr<6144>(bAd); bf1[3] = dsr<7168>(bAd); }
#define SB0 __builtin_amdgcn_sched_barrier(0)
#define CLUSTER(BV, NB) { \
    __builtin_amdgcn_s_setprio(1); \
    _Pragma("unroll") \
    for (int mi = 0; mi < 4; ++mi) \
      _Pragma("unroll") \
      for (int n = 0; n < 4; ++n) \
        acc[mi][n + NB] = __builtin_amdgcn_mfma_f32_16x16x32_bf16(af[mi], BV[n], acc[mi][n + NB], 0, 0, 0); \
    __builtin_amdgcn_s_setprio(0); }

  int NT = K >> 5;  // BK = 32
  STAGE(0, 0)
  VMCNT(0);
  __builtin_amdgcn_s_barrier();

  for (int t = 0; t < NT; ++t) {
    bool pf = (t + 1 < NT);
    if (pf) STAGE((t + 1) & 1, t + 1)
    READS_
    LGKM(4); SB0;
    CLUSTER(bf0, 0);
    LGKM(0); SB0;
    CLUSTER(bf1, 4);
    if (pf) {
      VMCNT(0);
      __builtin_amdgcn_s_barrier();
      aAd ^= 32768u; bAd ^= 32768u;
    }
  }

#undef READS_
#undef SB0
#undef CLUSTER
#undef STAGE

  // ---- epilogue ----
  int r0 = bm * 128 + wm * 64;
  int c0 = bn * 256 + wn * 128;
#pragma unroll
  for (int mi = 0; mi < 4; ++mi) {
    int rowb = r0 + mi * 16 + ((lane >> 4) << 2);
#pragma unroll
    for (int r = 0; r < 4; ++r) {
      int row = rowb + r;
      if (DO_GELU) {
#pragma unroll
        for (int n = 0; n < 8; ++n) {
          int col = c0 + n * 16 + (lane & 15);
          Hout[((size_t)e * M + row) * N + col] = f2bf(gelu_tanh(acc[mi][n][r]));
        }
      }
      if (FUSE_COMBINE) {
        int tkn = smap[e * CAP + row];
        if (tkn >= 0) {
          float gt = gate[tkn];
#pragma unroll
          for (int n = 0; n < 8; ++n) {
            int col = c0 + n * 16 + (lane & 15);
            out[(size_t)tkn * Dd + col] = acc[mi][n][r] * gt;
          }
        }
      }
    }
  }
}

extern "C" void kernel_launch(void* const* d_in, const int* in_sizes, int n_in,
                              void* d_out, int out_size, void* d_ws, size_t ws_size,
                              hipStream_t stream) {
  const float* x  = (const float*)d_in[0];
  const float* wg = (const float*)d_in[1];
  const float* w1 = (const float*)d_in[2];
  const float* w2 = (const float*)d_in[3];
  float* out = (float*)d_out;

  char* ws = (char*)d_ws;
  int*   idx  = (int*)(ws + 0);
  int*   pos  = (int*)(ws + 65536);
  float* gate = (float*)(ws + 131072);
  float* meP  = (float*)(ws + 196608);
  int*   smap = (int*)(ws + 327680);
  unsigned short* Xg  = (unsigned short*)(ws + 393216ull);
  unsigned short* W1T = (unsigned short*)(ws + 33947648ull);
  unsigned short* W2T = (unsigned short*)(ws + 101056512ull);
  unsigned short* H   = (unsigned short*)(ws + 168165376ull);

  hipMemsetAsync(smap, 0xFF, Ee * CAP * 4, stream);
  gating_kernel<<<Tt / 4, 256, 0, stream>>>(x, wg, idx, gate, meP);
  scan_kernel<<<1, 512, 0, stream>>>(idx, pos, smap, meP, Tt / 4,
                                     out + (size_t)Tt * Dd);
  zero_dropped<<<Tt, 256, 0, stream>>>(pos, out);
  transpose_cast<<<dim3(DFFf / 64, Dd / 64, Ee), 256, 0, stream>>>(w1, W1T, Dd, DFFf);
  transpose_cast<<<dim3(Dd / 64, DFFf / 64, Ee), 256, 0, stream>>>(w2, W2T, DFFf, Dd);
  build_xg<<<Ee * CAP, 256, 0, stream>>>(x, smap, Xg);
  gemm128_kernel<1, 0><<<dim3(CAP / 128, DFFf / 256, Ee), 256, 0, stream>>>(
      Xg, W1T, H, nullptr, nullptr, nullptr, CAP, DFFf, Dd);
  gemm128_kernel<0, 1><<<dim3(CAP / 128, Dd / 256, Ee), 256, 0, stream>>>(
      H, W2T, nullptr, smap, gate, out, CAP, Dd, DFFf);
}

// Round 8
// 507.664 us; speedup vs baseline: 1.0630x; 1.0630x over previous
//
#include <hip/hip_runtime.h>
#include <hip/hip_bf16.h>

#define Tt   16384
#define Dd   1024
#define Ee   8
#define CAP  2048
#define DFFf 4096

typedef __attribute__((ext_vector_type(8))) short bf16x8;
typedef __attribute__((ext_vector_type(4))) float f32x4;

__device__ __forceinline__ unsigned short f2bf(float f) {
  union { float f; unsigned u; } v; v.f = f;
  unsigned r = (v.u + 0x7FFFu + ((v.u >> 16) & 1u)) >> 16;
  return (unsigned short)r;
}

__device__ __forceinline__ float gelu_tanh(float x) {
  float z = 0.7978845608028654f * (x + 0.044715f * x * x * x);
  float az = fabsf(z);
  float t = __expf(-2.0f * az);
  float th = (1.0f - t) / (1.0f + t);
  th = (z < 0.0f) ? -th : th;
  return 0.5f * x * (1.0f + th);
}

__device__ __forceinline__ void gld16(const void* g, void* l) {
  __builtin_amdgcn_global_load_lds(
      (const __attribute__((address_space(1))) void*)g,
      (__attribute__((address_space(3))) void*)l,
      16, 0, 0);
}

template <int IMM>
__device__ __forceinline__ bf16x8 dsr(unsigned a) {
  bf16x8 r;
  asm volatile("ds_read_b128 %0, %1 offset:%c2" : "=v"(r) : "v"(a), "i"(IMM));
  return r;
}
#define LGKM(N) asm volatile("s_waitcnt lgkmcnt(" #N ")" ::: "memory")
#define VMCNT(N) asm volatile("s_waitcnt vmcnt(" #N ")" ::: "memory")

// ---------------- gating: logits fp32, softmax, argmax ----------------
__global__ __launch_bounds__(256) void gating_kernel(
    const float* __restrict__ x, const float* __restrict__ wg,
    int* __restrict__ idx, float* __restrict__ gate, float* __restrict__ meP) {
  int tid = threadIdx.x, lane = tid & 63, w = tid >> 6;
  int t = blockIdx.x * 4 + w;
  const float* xr = x + (size_t)t * Dd;
  float p[8];
#pragma unroll
  for (int e2 = 0; e2 < 8; ++e2) p[e2] = 0.f;
#pragma unroll
  for (int i = 0; i < 16; ++i) {
    int j = lane + (i << 6);
    float xv = xr[j];
    const float4* wr = (const float4*)(wg + j * 8);
    float4 a = wr[0], b = wr[1];
    p[0] += xv * a.x; p[1] += xv * a.y; p[2] += xv * a.z; p[3] += xv * a.w;
    p[4] += xv * b.x; p[5] += xv * b.y; p[6] += xv * b.z; p[7] += xv * b.w;
  }
#pragma unroll
  for (int off = 32; off > 0; off >>= 1)
#pragma unroll
    for (int e2 = 0; e2 < 8; ++e2) p[e2] += __shfl_xor(p[e2], off);
  __shared__ float smG[4][8];
  if (lane == 0) {
    float mx = p[0]; int am = 0;
#pragma unroll
    for (int e2 = 1; e2 < 8; ++e2) if (p[e2] > mx) { mx = p[e2]; am = e2; }
    float s = 0.f, g2[8];
#pragma unroll
    for (int e2 = 0; e2 < 8; ++e2) { g2[e2] = __expf(p[e2] - mx); s += g2[e2]; }
    float inv = 1.f / s;
    idx[t] = am;
    gate[t] = g2[am] * inv;
#pragma unroll
    for (int e2 = 0; e2 < 8; ++e2) smG[w][e2] = g2[e2] * inv;
  }
  __syncthreads();
  if (tid < 8)
    meP[blockIdx.x * 8 + tid] = smG[0][tid] + smG[1][tid] + smG[2][tid] + smG[3][tid];
}

// ------------- scan: per-expert cumulative position + l_aux -------------
__global__ __launch_bounds__(512) void scan_kernel(
    const int* __restrict__ idx, int* __restrict__ pos, int* __restrict__ smap,
    const float* __restrict__ meP, int nblkG, float* __restrict__ laux_out) {
  int tid = threadIdx.x, lane = tid & 63, e = tid >> 6;
  int running = 0;
  for (int c = 0; c < Tt; c += 256) {
    int m0 = idx[c + lane];
    int m1 = idx[c + 64 + lane];
    int m2 = idx[c + 128 + lane];
    int m3 = idx[c + 192 + lane];
#define RND(mv, base) { \
    unsigned long long mm = __ballot(mv == e); \
    int p = running + __popcll(mm & ((1ull << lane) - 1ull)); \
    if (mv == e) { pos[(base) + lane] = p; if (p < CAP) smap[e * CAP + p] = (base) + lane; } \
    running += (int)__popcll(mm); }
    RND(m0, c) RND(m1, c + 64) RND(m2, c + 128) RND(m3, c + 192)
#undef RND
  }
  __shared__ int scnt[8];
  __shared__ float smesum[8];
  __shared__ float red[512];
  if (lane == 0) scnt[e] = running;
  float part = 0.f;
  int ee = tid & 7, b0 = tid >> 3;
  for (int b = b0; b < nblkG; b += 64) part += meP[b * 8 + ee];
  red[tid] = part;
  __syncthreads();
  if (tid < 8) {
    float s = 0.f;
    for (int i = 0; i < 64; ++i) s += red[i * 8 + tid];
    smesum[tid] = s;
  }
  __syncthreads();
  if (tid == 0) {
    float l = 0.f;
    for (int q = 0; q < 8; ++q) l += smesum[q] * (float)scnt[q];
    laux_out[0] = l * 8.0f / ((float)Tt * (float)Tt);
  }
}

// ------------- zero dropped-token output rows -------------
__global__ __launch_bounds__(256) void zero_dropped(
    const int* __restrict__ pos, float* __restrict__ out) {
  int t = blockIdx.x;
  if (pos[t] < CAP) return;
  ((float4*)(out + (size_t)t * Dd))[threadIdx.x] = make_float4(0.f, 0.f, 0.f, 0.f);
}

// ------------- transpose + cast fp32 -> bf16 (B^T weight layout) -------------
__global__ __launch_bounds__(256) void transpose_cast(
    const float* __restrict__ src, unsigned short* __restrict__ dst, int R, int Cn) {
  __shared__ float tile[64][65];
  int e = blockIdx.z;
  const float* s = src + (size_t)e * R * Cn;
  unsigned short* d = dst + (size_t)e * R * Cn;
  int c = threadIdx.x & 63;
  int r0 = threadIdx.x >> 6;
  int rb = blockIdx.y * 64, cb = blockIdx.x * 64;
#pragma unroll
  for (int i = 0; i < 16; ++i) {
    int r = r0 + i * 4;
    tile[r][c] = s[(size_t)(rb + r) * Cn + cb + c];
  }
  __syncthreads();
#pragma unroll
  for (int i = 0; i < 16; ++i) {
    int r = r0 + i * 4;
    d[(size_t)(cb + r) * R + rb + c] = f2bf(tile[c][r]);
  }
}

// ------------- gather + cast dispatched tokens -------------
__global__ __launch_bounds__(256) void build_xg(
    const float* __restrict__ x, const int* __restrict__ smap,
    unsigned short* __restrict__ Xg) {
  int row = blockIdx.x;
  int t = smap[row];
  int j = threadIdx.x;
  float4 v = make_float4(0.f, 0.f, 0.f, 0.f);
  if (t >= 0) v = ((const float4*)(x + (size_t)t * Dd))[j];
  ushort4 o;
  o.x = f2bf(v.x); o.y = f2bf(v.y); o.z = f2bf(v.z); o.w = f2bf(v.w);
  ((ushort4*)(Xg + (size_t)row * Dd))[j] = o;
}

// ------------- 256^2-tile bf16 MFMA GEMM (B^T), m201-style 4-phase/K-tile -----
// 8 waves (2M x 4N), per-wave 128x64, BK=64 split in 2 K-halves (staging unit =
// K-half: 256 rows x 32 k = 16 KB, 2 gld16/thread). Phases (kh,mh):
// (0,0)(0,1)(1,0)(1,1); stage order {A-kh0,B-kh0,A-kh1,B-kh1}(t+1); vmcnt(4) at
// P2/P4-ends only (3-4 phase cover, never 0 in steady loop). Per phase:
// reads+stage -> barrier -> lgkm(0) -> setprio(1) -> 16 MFMA -> barrier.
// LDS per region: rows 2l,2l+1 share a 128-B line, col = ((row&1)<<2)|(g^((row>>1)&3))
// (bijective; 8-lane frag group hits all 8 granule columns; staging dest linear).
template <int DO_GELU, int FUSE_COMBINE>
__global__ __launch_bounds__(512, 2) void gemm8p_kernel(
    const unsigned short* __restrict__ A,   // [E][M][K] bf16
    const unsigned short* __restrict__ BT,  // [E][N][K] bf16
    unsigned short* __restrict__ Hout,      // [E][M][N] bf16 (GEMM1)
    const int* __restrict__ smap,           // [E][CAP] token map (GEMM2)
    const float* __restrict__ gate,         // [T]
    float* __restrict__ out,                // [T][D]
    int M, int N, int K) {
  __shared__ char lds[131072];  // [buf:65536][A-kh0:16K][A-kh1][B-kh0][B-kh1]
  int tid = threadIdx.x, lane = tid & 63, w = tid >> 6;
  int wm = w >> 2, wn = w & 3;

  // bijective XCD-aware swizzle (nwg % 8 == 0)
  int gx = gridDim.x, gy = gridDim.y;
  long gid = blockIdx.x + (long)gx * (blockIdx.y + (long)gy * blockIdx.z);
  int nT = gx * gy * (int)gridDim.z;
  int cpx = nT >> 3;
  int swz = (int)((gid & 7) * (long)cpx + (gid >> 3));
  int bn = swz % gx;
  int bm = (swz / gx) % gy;
  int e  = swz / (gx * gy);

  const char* Ab = (const char*)(A + ((size_t)e * M + (size_t)bm * 256) * K);
  const char* Bb = (const char*)(BT + ((size_t)e * N + (size_t)bn * 256) * K);
  int K2 = K * 2;

  // staging source offsets (thread-const): region-local phys p=q*8192+tid*16
  // line=p>>7, col=(p>>4)&7 -> row=2*line+(col>>2), g=(col&3)^(line&3)
  unsigned sv0, sv1;
  {
    int p = tid * 16, line = p >> 7, col = (p >> 4) & 7;
    sv0 = (unsigned)((2 * line + (col >> 2)) * K2 + (((col & 3) ^ (line & 3)) << 4));
    p = 8192 + tid * 16; line = p >> 7; col = (p >> 4) & 7;
    sv1 = (unsigned)((2 * line + (col >> 2)) * K2 + (((col & 3) ^ (line & 3)) << 4));
  }

  // OP: 0=A,1=B; KH: k-half; T: K-tile; D: dest buf
#define STAGE(OP, KH, T, D) { \
    const char* s_ = (OP ? Bb : Ab) + (unsigned)(T) * 128u + (KH) * 64u; \
    char* d_ = (char*)lds + (D) * 65536 + (OP) * 32768 + (KH) * 16384 + tid * 16; \
    gld16(s_ + sv0, d_); gld16(s_ + sv1, d_ + 8192); }

  // fragment LDS addresses (buf0, kh0): imm offsets add kh*16384 + mh*4096 + mi*1024
  unsigned lb = (unsigned)(size_t)(__attribute__((address_space(3))) char*)lds;
  int arow = wm * 128 + (lane & 15);
  int brow = wn * 64 + (lane & 15);
  unsigned g0 = (unsigned)(lane >> 4);
  unsigned aAd = lb + (unsigned)((arow >> 1) * 128 +
                ((((arow & 1) << 2) | (g0 ^ ((arow >> 1) & 3))) << 4));
  unsigned bAd = lb + 32768u + (unsigned)((brow >> 1) * 128 +
                ((((brow & 1) << 2) | (g0 ^ ((brow >> 1) & 3))) << 4));

  f32x4 acc[2][4][4];
#pragma unroll
  for (int mh = 0; mh < 2; ++mh)
#pragma unroll
    for (int mi = 0; mi < 4; ++mi)
#pragma unroll
      for (int n = 0; n < 4; ++n) acc[mh][mi][n] = (f32x4){0.f, 0.f, 0.f, 0.f};

  bf16x8 a[4], b[4];
#define SB0 __builtin_amdgcn_sched_barrier(0)
#define MFMA16(MH_) { \
    __builtin_amdgcn_s_setprio(1); \
    _Pragma("unroll") \
    for (int mi = 0; mi < 4; ++mi) \
      _Pragma("unroll") \
      for (int n = 0; n < 4; ++n) \
        acc[MH_][mi][n] = __builtin_amdgcn_mfma_f32_16x16x32_bf16(a[mi], b[n], acc[MH_][mi][n], 0, 0, 0); \
    __builtin_amdgcn_s_setprio(0); }
#define BAR __builtin_amdgcn_s_barrier()

  int NT = K >> 6;
  // prologue: stage tile0 fully into buf0
  STAGE(0, 0, 0, 0) STAGE(1, 0, 0, 0) STAGE(0, 1, 0, 0) STAGE(1, 1, 0, 0)
  VMCNT(0);
  BAR;

  for (int t = 0; t < NT - 1; ++t) {
    int d = (t & 1) ^ 1;
    // ---- P1: kh0, mh0 ---- (reads 8; stage A-kh0(t+1))
    b[0] = dsr<0>(bAd); b[1] = dsr<1024>(bAd); b[2] = dsr<2048>(bAd); b[3] = dsr<3072>(bAd);
    a[0] = dsr<0>(aAd); a[1] = dsr<1024>(aAd); a[2] = dsr<2048>(aAd); a[3] = dsr<3072>(aAd);
    STAGE(0, 0, t + 1, d)
    BAR; LGKM(0); SB0;
    MFMA16(0)
    BAR;
    // ---- P2: kh0, mh1 ---- (reads 4; stage B-kh0(t+1); drain A/B-kh1(t))
    a[0] = dsr<4096>(aAd); a[1] = dsr<5120>(aAd); a[2] = dsr<6144>(aAd); a[3] = dsr<7168>(aAd);
    STAGE(1, 0, t + 1, d)
    BAR; LGKM(0); SB0;
    MFMA16(1)
    VMCNT(4);
    BAR;
    // ---- P3: kh1, mh0 ---- (reads 8; stage A-kh1(t+1))
    b[0] = dsr<16384>(bAd); b[1] = dsr<17408>(bAd); b[2] = dsr<18432>(bAd); b[3] = dsr<19456>(bAd);
    a[0] = dsr<16384>(aAd); a[1] = dsr<17408>(aAd); a[2] = dsr<18432>(aAd); a[3] = dsr<19456>(aAd);
    STAGE(0, 1, t + 1, d)
    BAR; LGKM(0); SB0;
    MFMA16(0)
    BAR;
    // ---- P4: kh1, mh1 ---- (reads 4; stage B-kh1(t+1); drain A/B-kh0(t+1))
    a[0] = dsr<20480>(aAd); a[1] = dsr<21504>(aAd); a[2] = dsr<22528>(aAd); a[3] = dsr<23552>(aAd);
    STAGE(1, 1, t + 1, d)
    BAR; LGKM(0); SB0;
    MFMA16(1)
    VMCNT(4);
    BAR;
    aAd ^= 65536u; bAd ^= 65536u;
  }

  // ---- peeled last tile (no staging) ----
  b[0] = dsr<0>(bAd); b[1] = dsr<1024>(bAd); b[2] = dsr<2048>(bAd); b[3] = dsr<3072>(bAd);
  a[0] = dsr<0>(aAd); a[1] = dsr<1024>(aAd); a[2] = dsr<2048>(aAd); a[3] = dsr<3072>(aAd);
  BAR; LGKM(0); SB0;
  MFMA16(0)
  BAR;
  a[0] = dsr<4096>(aAd); a[1] = dsr<5120>(aAd); a[2] = dsr<6144>(aAd); a[3] = dsr<7168>(aAd);
  LGKM(0); SB0;
  MFMA16(1)
  VMCNT(0);  // drain prev tile's P3/P4 stages (A/B-kh1 of this tile)
  BAR;
  b[0] = dsr<16384>(bAd); b[1] = dsr<17408>(bAd); b[2] = dsr<18432>(bAd); b[3] = dsr<19456>(bAd);
  a[0] = dsr<16384>(aAd); a[1] = dsr<17408>(aAd); a[2] = dsr<18432>(aAd); a[3] = dsr<19456>(aAd);
  LGKM(0); SB0;
  MFMA16(0)
  a[0] = dsr<20480>(aAd); a[1] = dsr<21504>(aAd); a[2] = dsr<22528>(aAd); a[3] = dsr<23552>(aAd);
  LGKM(0); SB0;
  MFMA16(1)

#undef BAR
#undef MFMA16
#undef SB0
#undef STAGE

  // ---- epilogue ----
  int r0 = bm * 256 + wm * 128;
  int c0 = bn * 256 + wn * 64;
#pragma unroll
  for (int mh = 0; mh < 2; ++mh)
#pragma unroll
    for (int mi = 0; mi < 4; ++mi) {
      int rowb = r0 + mh * 64 + mi * 16 + ((lane >> 4) << 2);
#pragma unroll
      for (int r = 0; r < 4; ++r) {
        int row = rowb + r;
        if (DO_GELU) {
#pragma unroll
          for (int n = 0; n < 4; ++n) {
            int col = c0 + n * 16 + (lane & 15);
            Hout[((size_t)e * M + row) * N + col] = f2bf(gelu_tanh(acc[mh][mi][n][r]));
          }
        }
        if (FUSE_COMBINE) {
          int tkn = smap[e * CAP + row];
          if (tkn >= 0) {
            float gt = gate[tkn];
#pragma unroll
            for (int n = 0; n < 4; ++n) {
              int col = c0 + n * 16 + (lane & 15);
              out[(size_t)tkn * Dd + col] = acc[mh][mi][n][r] * gt;
            }
          }
        }
      }
    }
}

extern "C" void kernel_launch(void* const* d_in, const int* in_sizes, int n_in,
                              void* d_out, int out_size, void* d_ws, size_t ws_size,
                              hipStream_t stream) {
  const float* x  = (const float*)d_in[0];
  const float* wg = (const float*)d_in[1];
  const float* w1 = (const float*)d_in[2];
  const float* w2 = (const float*)d_in[3];
  float* out = (float*)d_out;

  char* ws = (char*)d_ws;
  int*   idx  = (int*)(ws + 0);
  int*   pos  = (int*)(ws + 65536);
  float* gate = (float*)(ws + 131072);
  float* meP  = (float*)(ws + 196608);
  int*   smap = (int*)(ws + 327680);
  unsigned short* Xg  = (unsigned short*)(ws + 393216ull);
  unsigned short* W1T = (unsigned short*)(ws + 33947648ull);
  unsigned short* W2T = (unsigned short*)(ws + 101056512ull);
  unsigned short* H   = (unsigned short*)(ws + 168165376ull);

  hipMemsetAsync(smap, 0xFF, Ee * CAP * 4, stream);
  gating_kernel<<<Tt / 4, 256, 0, stream>>>(x, wg, idx, gate, meP);
  scan_kernel<<<1, 512, 0, stream>>>(idx, pos, smap, meP, Tt / 4,
                                     out + (size_t)Tt * Dd);
  zero_dropped<<<Tt, 256, 0, stream>>>(pos, out);
  transpose_cast<<<dim3(DFFf / 64, Dd / 64, Ee), 256, 0, stream>>>(w1, W1T, Dd, DFFf);
  transpose_cast<<<dim3(Dd / 64, DFFf / 64, Ee), 256, 0, stream>>>(w2, W2T, DFFf, Dd);
  build_xg<<<Ee * CAP, 256, 0, stream>>>(x, smap, Xg);
  gemm8p_kernel<1, 0><<<dim3(DFFf / 256, CAP / 256, Ee), 512, 0, stream>>>(
      Xg, W1T, H, nullptr, nullptr, nullptr, CAP, DFFf, Dd);
  gemm8p_kernel<0, 1><<<dim3(Dd / 256, CAP / 256, Ee), 512, 0, stream>>>(
      H, W2T, nullptr, smap, gate, out, CAP, Dd, DFFf);
}